// Round 4
// baseline (1761.918 us; speedup 1.0000x reference)
//
#include <hip/hip_runtime.h>
#include <hip/hip_bf16.h>

// ---------------------------------------------------------------------------
// PointNet++ critic forward. fp32. B=32, N=4096.
// R4: (1) dense layers: compile-time KC + unroll-8 -> immediate-offset LDS
// reads, SGPR-folded weight offsets, no prefetch movs. (2) ball query: block
// stages all points in LDS, 16 waves share. (3) FPS: coords in registers.
// ---------------------------------------------------------------------------

// ======================= DPP wave64 max-reduce (u64) =======================
template<int CTRL>
__device__ __forceinline__ unsigned long long dpp_mov_u64(unsigned long long x) {
    const int lo = (int)(unsigned)(x & 0xffffffffull);
    const int hi = (int)(unsigned)(x >> 32);
    const int nlo = __builtin_amdgcn_update_dpp(lo, lo, CTRL, 0xf, 0xf, false);
    const int nhi = __builtin_amdgcn_update_dpp(hi, hi, CTRL, 0xf, 0xf, false);
    return ((unsigned long long)(unsigned)nhi << 32) | (unsigned)nlo;
}

// After this, lane 63 holds the max over all 64 lanes.
__device__ __forceinline__ unsigned long long wave_max_u64(unsigned long long x) {
    unsigned long long y;
    y = dpp_mov_u64<0x111>(x); if (y > x) x = y;   // row_shr:1
    y = dpp_mov_u64<0x112>(x); if (y > x) x = y;   // row_shr:2
    y = dpp_mov_u64<0x114>(x); if (y > x) x = y;   // row_shr:4
    y = dpp_mov_u64<0x118>(x); if (y > x) x = y;   // row_shr:8
    y = dpp_mov_u64<0x142>(x); if (y > x) x = y;   // row_bcast:15
    y = dpp_mov_u64<0x143>(x); if (y > x) x = y;   // row_bcast:31
    return x;
}

// ============================ FPS ==========================================
// Coords live in registers (px/py/pz[P]); LDS float4 copy only for the random
// centroid lookup (one broadcast ds_read_b128 per iteration).
template<int N, int S, int NT, bool CHW>
__global__ __launch_bounds__(NT)
void fps_kernel(const float* __restrict__ xyz, float* __restrict__ new_xyz) {
    constexpr int P  = N / NT;
    constexpr int NW = NT / 64;
    __shared__ __align__(16) float4 sxyz[N];
    __shared__ __align__(16) unsigned long long rv[2][NW > 1 ? NW : 2];
    const int b = blockIdx.x, t = threadIdx.x;
    float px[P], py[P], pz[P], dist[P];
    if (CHW) {
        const float* base = xyz + (size_t)b * 3 * N;
        #pragma unroll
        for (int p = 0; p < P; ++p) {
            const int i = p * NT + t;
            px[p] = base[i]; py[p] = base[N + i]; pz[p] = base[2 * N + i];
            sxyz[i] = make_float4(px[p], py[p], pz[p], 0.0f);
        }
    } else {
        const float* base = xyz + (size_t)b * N * 3;
        #pragma unroll
        for (int p = 0; p < P; ++p) {
            const int i = p * NT + t;
            px[p] = base[i*3]; py[p] = base[i*3+1]; pz[p] = base[i*3+2];
            sxyz[i] = make_float4(px[p], py[p], pz[p], 0.0f);
        }
    }
    #pragma unroll
    for (int p = 0; p < P; ++p) dist[p] = 1e10f;
    __syncthreads();
    int far = 0;
    float* out = new_xyz + (size_t)b * S * 3;
    for (int j = 0; j < S; ++j) {
        const float4 cen = sxyz[far];            // broadcast b128
        if (t == 0) { out[j*3+0] = cen.x; out[j*3+1] = cen.y; out[j*3+2] = cen.z; }
        float bv = -1.0f; int bi = 0;
        #pragma unroll
        for (int p = 0; p < P; ++p) {
            const int i = p * NT + t;
            const float dx = px[p] - cen.x, dy = py[p] - cen.y, dz = pz[p] - cen.z;
            // match reference rounding exactly: no FMA contraction
            const float d = __fadd_rn(__fadd_rn(__fmul_rn(dx, dx), __fmul_rn(dy, dy)), __fmul_rn(dz, dz));
            const float nd = fminf(dist[p], d);
            dist[p] = nd;
            if (nd > bv) { bv = nd; bi = i; }    // strict > keeps smallest i
        }
        unsigned long long pk =
            ((unsigned long long)__float_as_uint(bv) << 32) | (unsigned)(N - 1 - bi);
        pk = wave_max_u64(pk);
        if constexpr (NW > 1) {
            const int sl = j & 1;
            if ((t & 63) == 63) rv[sl][t >> 6] = pk;
            __syncthreads();
            unsigned long long best = rv[sl][0];
            #pragma unroll
            for (int w = 1; w < NW; ++w) { const unsigned long long v = rv[sl][w]; if (v > best) best = v; }
            far = N - 1 - (int)(best & 0xffffffffull);
        } else {
            far = N - 1 - __builtin_amdgcn_readlane((int)(pk & 0xffffffffull), 63);
        }
    }
}

// ============================ Ball query ===================================
// One block = WPB waves = WPB centroids (same batch). All points staged in LDS
// once; each wave scans LDS with ballot compaction + early exit.
template<int N, int NS, bool CHW, int NT>
__global__ __launch_bounds__(NT)
void bq_kernel(float r2, const float* __restrict__ xyz, const float* __restrict__ cen,
               int* __restrict__ gidx, int S) {
    constexpr int WPB = NT / 64;
    __shared__ __align__(16) float4 sp[N];
    const int t = threadIdx.x, lane = t & 63, w = t >> 6;
    const int cen0 = blockIdx.x * WPB;
    const int b = cen0 / S;                     // WPB divides S -> same batch
    if (CHW) {
        const float* base = xyz + (size_t)b * 3 * N;
        for (int i = t; i < N; i += NT)
            sp[i] = make_float4(base[i], base[N + i], base[2 * N + i], 0.0f);
    } else {
        const float* base = xyz + (size_t)b * N * 3;
        for (int i = t; i < N; i += NT)
            sp[i] = make_float4(base[i*3], base[i*3+1], base[i*3+2], 0.0f);
    }
    __syncthreads();
    const int wid = cen0 + w;
    const float cx = cen[(size_t)wid*3+0], cy = cen[(size_t)wid*3+1], cz = cen[(size_t)wid*3+2];
    int* out = gidx + (size_t)wid * NS;
    int cnt = 0, first = -1;
    for (int b0 = 0; b0 < N; b0 += 64) {
        const float4 p = sp[b0 + lane];
        const float dx = p.x - cx, dy = p.y - cy, dz = p.z - cz;
        const float d = __fadd_rn(__fadd_rn(__fmul_rn(dx, dx), __fmul_rn(dy, dy)), __fmul_rn(dz, dz));
        const bool in = (d <= r2);
        const unsigned long long m = __ballot(in);
        if (first < 0 && m != 0ull) first = b0 + __ffsll((unsigned long long)m) - 1;
        const int pos = cnt + (int)__popcll(m & ((1ull << lane) - 1ull));
        if (in && pos < NS) out[pos] = b0 + lane;
        cnt += (int)__popcll(m);
        if (cnt >= NS) break;
    }
    if (cnt < NS)
        for (int k = cnt + lane; k < NS; k += 64) out[k] = first;
}

// ==================== weight pre-transpose (fused, one launch) =============
__device__ __forceinline__ void wt4_one(const float* __restrict__ w, float4* __restrict__ out,
                                        int O, int K, int reorder, int i) {
    const int o = i % O, cc = i / O;
    float v[4];
    #pragma unroll
    for (int u = 0; u < 4; ++u) {
        const int cp = cc * 4 + u;
        int c;
        if (reorder) c = (cp < K - 3) ? cp + 3 : (cp < K ? cp - (K - 3) : -1);
        else         c = (cp < K) ? cp : -1;
        v[u] = (c >= 0) ? w[(size_t)o * K + c] : 0.0f;
    }
    out[(size_t)cc * O + o] = make_float4(v[0], v[1], v[2], v[3]);
}

__global__ __launch_bounds__(256)
void wt4all_kernel(const float* w10, float4* o10, const float* w11, float4* o11,
                   const float* w12, float4* o12, const float* w20, float4* o20,
                   const float* w21, float4* o21, const float* w22, float4* o22) {
    int i = blockIdx.x * 256 + threadIdx.x;
    if (i < 64)        { wt4_one(w10, o10,  64,   3, 0, i); return; }       i -= 64;
    if (i < 1024)      { wt4_one(w11, o11,  64,  64, 0, i); return; }       i -= 1024;
    if (i < 2048)      { wt4_one(w12, o12, 128,  64, 0, i); return; }       i -= 2048;
    if (i < 4224)      { wt4_one(w20, o20, 128, 131, 1, i); return; }       i -= 4224;
    if (i < 4096)      { wt4_one(w21, o21, 128, 128, 0, i); return; }       i -= 4096;
    if (i < 8192)      { wt4_one(w22, o22, 256, 128, 0, i); return; }
}

// ===================== dense layer (global weights, LDS acts) ==============
// Compile-time KC: cc loop unrolls (8) -> LDS reads use offset immediates,
// weight-address uniform part folds to SGPR adds, loads hoist far ahead.
template<int O, int SIN, int SOUT, int KC>
__device__ __forceinline__ void dense_relu(
    const float4* __restrict__ W4, const float* __restrict__ bias,
    const float* __restrict__ in, float* __restrict__ out, int t) {
    constexpr int Q   = O / 4;
    constexpr int RPT = Q / 4;
    constexpr int NB  = (RPT + 7) / 8;
    constexpr int RB  = RPT < 8 ? RPT : 8;
    const int q = t & (Q - 1);
    const int rg = t / Q;
    const int n0 = rg * RPT;
    float bb[4];
    #pragma unroll
    for (int j = 0; j < 4; ++j) bb[j] = bias[q + Q * j];
    #pragma unroll
    for (int nb = 0; nb < NB; ++nb) {
        float acc[RB][4];
        #pragma unroll
        for (int k = 0; k < RB; ++k)
            #pragma unroll
            for (int j = 0; j < 4; ++j) acc[k][j] = bb[j];
        #pragma unroll 8
        for (int cc = 0; cc < KC; ++cc) {
            float4 w[4];
            #pragma unroll
            for (int j = 0; j < 4; ++j) w[j] = W4[cc * O + q + Q * j];
            #pragma unroll
            for (int k = 0; k < RB; ++k) {
                const float4 xv = *(const float4*)&in[(n0 + nb * 8 + k) * SIN + cc * 4];
                #pragma unroll
                for (int j = 0; j < 4; ++j)
                    acc[k][j] += w[j].x * xv.x + w[j].y * xv.y + w[j].z * xv.z + w[j].w * xv.w;
            }
        }
        #pragma unroll
        for (int k = 0; k < RB; ++k)
            #pragma unroll
            for (int j = 0; j < 4; ++j)
                out[(n0 + nb * 8 + k) * SOUT + q + Q * j] = fmaxf(acc[k][j], 0.0f);
    }
}

template<int O, int SIN, int KC>
__device__ __forceinline__ void dense_relu_max(
    const float4* __restrict__ W4, const float* __restrict__ bias,
    const float* __restrict__ in, float* __restrict__ red, int t) {
    constexpr int Q   = O / 4;
    constexpr int RPT = Q / 4;
    constexpr int NB  = (RPT + 7) / 8;
    constexpr int RB  = RPT < 8 ? RPT : 8;
    const int q = t & (Q - 1);
    const int rg = t / Q;
    const int n0 = rg * RPT;
    float bb[4], m[4];
    #pragma unroll
    for (int j = 0; j < 4; ++j) { bb[j] = bias[q + Q * j]; m[j] = 0.0f; }
    #pragma unroll
    for (int nb = 0; nb < NB; ++nb) {
        float acc[RB][4];
        #pragma unroll
        for (int k = 0; k < RB; ++k)
            #pragma unroll
            for (int j = 0; j < 4; ++j) acc[k][j] = bb[j];
        #pragma unroll 8
        for (int cc = 0; cc < KC; ++cc) {
            float4 w[4];
            #pragma unroll
            for (int j = 0; j < 4; ++j) w[j] = W4[cc * O + q + Q * j];
            #pragma unroll
            for (int k = 0; k < RB; ++k) {
                const float4 xv = *(const float4*)&in[(n0 + nb * 8 + k) * SIN + cc * 4];
                #pragma unroll
                for (int j = 0; j < 4; ++j)
                    acc[k][j] += w[j].x * xv.x + w[j].y * xv.y + w[j].z * xv.z + w[j].w * xv.w;
            }
        }
        #pragma unroll
        for (int k = 0; k < RB; ++k)
            #pragma unroll
            for (int j = 0; j < 4; ++j) m[j] = fmaxf(m[j], fmaxf(acc[k][j], 0.0f));
    }
    #pragma unroll
    for (int j = 0; j < 4; ++j) red[rg * O + q + Q * j] = m[j];
}

// ============================ MLP stage 1 ==================================
__global__ __launch_bounds__(256, 4)
void mlp1_kernel(const float* __restrict__ xyz, const float* __restrict__ l1xyz,
                 const int* __restrict__ gidx,
                 const float4* __restrict__ W40, const float* __restrict__ b0,
                 const float4* __restrict__ W41, const float* __restrict__ b1,
                 const float4* __restrict__ W42, const float* __restrict__ b2,
                 float* __restrict__ l1p) {
    __shared__ __align__(16) float g[64 * 4];
    __shared__ __align__(16) float h1[64 * 68];
    __shared__ __align__(16) float h2[64 * 68];
    __shared__ float red[1024];
    const int t = threadIdx.x;
    const int b = blockIdx.y, s0 = blockIdx.x * 2;
    {
        const int n = t >> 2, c = t & 3;
        const int s = s0 + (n >> 5);
        const int gi = gidx[((size_t)b * 512 + s) * 32 + (n & 31)];
        float v = 0.0f;
        if (c < 3) v = xyz[(size_t)b * 3 * 4096 + c * 4096 + gi] - l1xyz[((size_t)b * 512 + s) * 3 + c];
        g[n * 4 + c] = v;
    }
    __syncthreads();
    dense_relu<64, 4, 68, 1>(W40, b0, g, h1, t);
    __syncthreads();
    dense_relu<64, 68, 68, 16>(W41, b1, h1, h2, t);
    __syncthreads();
    dense_relu_max<128, 68, 16>(W42, b2, h2, red, t);
    __syncthreads();
    {
        const int half = t >> 7, o = t & 127;
        float v = red[(half * 4 + 0) * 128 + o];
        v = fmaxf(v, red[(half * 4 + 1) * 128 + o]);
        v = fmaxf(v, red[(half * 4 + 2) * 128 + o]);
        v = fmaxf(v, red[(half * 4 + 3) * 128 + o]);
        l1p[((size_t)b * 512 + s0 + half) * 128 + o] = v;
    }
}

// ============================ MLP stage 2 ==================================
__global__ __launch_bounds__(256, 2)
void mlp2_kernel(const float* __restrict__ l1xyz, const float* __restrict__ l1p,
                 const float* __restrict__ l2xyz, const int* __restrict__ gidx,
                 const float4* __restrict__ W40, const float* __restrict__ b0,
                 const float4* __restrict__ W41, const float* __restrict__ b1,
                 const float4* __restrict__ W42, const float* __restrict__ b2,
                 float* __restrict__ X3) {
    __shared__ __align__(16) float xb[64 * 132];
    __shared__ __align__(16) float h1[64 * 128];
    __shared__ float red[1024];
    __shared__ int sg[64];
    const int t = threadIdx.x, bs = blockIdx.x, b = bs >> 7;
    if (t < 64) sg[t] = gidx[(size_t)bs * 64 + t];
    if (t < 3)  X3[(size_t)bs * 259 + t] = l2xyz[(size_t)bs * 3 + t];   // raw coords
    __syncthreads();
    {
        for (int i = t; i < 64 * 32; i += 256) {
            const int n = i >> 5, cc = i & 31;
            const float4 v = *(const float4*)&l1p[((size_t)b * 512 + sg[n]) * 128 + cc * 4];
            *(float4*)&xb[n * 132 + cc * 4] = v;
        }
        if (t < 192) {
            const int n = t / 3, c = t % 3;
            xb[n * 132 + 128 + c] =
                l1xyz[((size_t)b * 512 + sg[n]) * 3 + c] - l2xyz[(size_t)bs * 3 + c];
        }
        if (t < 64) xb[t * 132 + 131] = 0.0f;
    }
    __syncthreads();
    dense_relu<128, 132, 128, 33>(W40, b0, xb, h1, t);
    __syncthreads();
    dense_relu<128, 128, 128, 32>(W41, b1, h1, xb, t);
    __syncthreads();
    dense_relu_max<256, 128, 32>(W42, b2, xb, red, t);
    __syncthreads();
    {
        float v = red[t];
        v = fmaxf(v, red[256 + t]);
        v = fmaxf(v, red[512 + t]);
        v = fmaxf(v, red[768 + t]);
        X3[(size_t)bs * 259 + 3 + t] = v;
    }
}

// ============================ Generic GEMM =================================
template<bool RELU>
__global__ __launch_bounds__(256)
void gemm_kernel(const float* __restrict__ A, const float* __restrict__ W,
                 const float* __restrict__ bias, float* __restrict__ C,
                 int M, int K, int O) {
    __shared__ __align__(16) float At[32*68];
    __shared__ __align__(16) float Wt[32*68];
    const int t = threadIdx.x;
    const int mtile = blockIdx.x * 64, otile = blockIdx.y * 64;
    const int tx = t & 15, ty = t >> 4;
    float acc[4][4];
    #pragma unroll
    for (int i = 0; i < 4; ++i)
        #pragma unroll
        for (int j = 0; j < 4; ++j) acc[i][j] = 0.0f;
    const int kk = t & 31, r0 = t >> 5;
    for (int k0 = 0; k0 < K; k0 += 32) {
        #pragma unroll
        for (int rr = 0; rr < 8; ++rr) {
            const int row = r0 + rr * 8;
            const int m = mtile + row, o = otile + row, k = k0 + kk;
            At[kk*68 + row] = (m < M && k < K) ? A[(size_t)m*K + k] : 0.0f;
            Wt[kk*68 + row] = (o < O && k < K) ? W[(size_t)o*K + k] : 0.0f;
        }
        __syncthreads();
        #pragma unroll
        for (int k2 = 0; k2 < 32; ++k2) {
            const float4 av = *(const float4*)&At[k2*68 + tx*4];
            const float4 wv = *(const float4*)&Wt[k2*68 + ty*4];
            const float a[4] = {av.x, av.y, av.z, av.w};
            const float w[4] = {wv.x, wv.y, wv.z, wv.w};
            #pragma unroll
            for (int i = 0; i < 4; ++i)
                #pragma unroll
                for (int j = 0; j < 4; ++j) acc[i][j] += a[i] * w[j];
        }
        __syncthreads();
    }
    #pragma unroll
    for (int i = 0; i < 4; ++i) {
        const int m = mtile + tx*4 + i;
        if (m >= M) continue;
        #pragma unroll
        for (int j = 0; j < 4; ++j) {
            const int o = otile + ty*4 + j;
            if (o >= O) continue;
            float v = acc[i][j] + bias[o];
            if (RELU) v = fmaxf(v, 0.0f);
            C[(size_t)m*O + o] = v;
        }
    }
}

// ============================ small utilities ==============================
__global__ __launch_bounds__(256)
void max128_kernel(const float* __restrict__ Y, float* __restrict__ feat) {
    const int idx = blockIdx.x * 256 + threadIdx.x;  // 32*1024
    const int b = idx >> 10, o = idx & 1023;
    const float* p = Y + (size_t)b * 128 * 1024 + o;
    float m = p[0];
    for (int n = 1; n < 128; ++n) m = fmaxf(m, p[(size_t)n * 1024]);
    feat[idx] = m;
}

// ============================ launch =======================================
extern "C" void kernel_launch(void* const* d_in, const int* in_sizes, int n_in,
                              void* d_out, int out_size, void* d_ws, size_t ws_size,
                              hipStream_t stream) {
    const float* xyz  = (const float*)d_in[0];
    const float* s1w0 = (const float*)d_in[1];  const float* s1b0 = (const float*)d_in[2];
    const float* s1w1 = (const float*)d_in[3];  const float* s1b1 = (const float*)d_in[4];
    const float* s1w2 = (const float*)d_in[5];  const float* s1b2 = (const float*)d_in[6];
    const float* s2w0 = (const float*)d_in[7];  const float* s2b0 = (const float*)d_in[8];
    const float* s2w1 = (const float*)d_in[9];  const float* s2b1 = (const float*)d_in[10];
    const float* s2w2 = (const float*)d_in[11]; const float* s2b2 = (const float*)d_in[12];
    const float* s3w0 = (const float*)d_in[13]; const float* s3b0 = (const float*)d_in[14];
    const float* s3w1 = (const float*)d_in[15]; const float* s3b1 = (const float*)d_in[16];
    const float* s3w2 = (const float*)d_in[17]; const float* s3b2 = (const float*)d_in[18];
    const float* f1w  = (const float*)d_in[19]; const float* f1b  = (const float*)d_in[20];
    const float* f2w  = (const float*)d_in[21]; const float* f2b  = (const float*)d_in[22];
    const float* f3w  = (const float*)d_in[23]; const float* f3b  = (const float*)d_in[24];

    char* ws = (char*)d_ws;
    float* l1_xyz = (float*)(ws + 0);              // 32*512*3
    int*   gidx1  = (int*)  (ws + 196608);         // 32*512*32
    float* l1p    = (float*)(ws + 2293760);        // 32*512*128
    float* l2_xyz = (float*)(ws + 10682368);       // 32*128*3
    int*   gidx2  = (int*)  (ws + 10731520);       // 32*128*64
    float* X3     = (float*)(ws + 11780096);       // 32*128*259
    float* Y1     = (float*)(ws + 16023552);       // 4096*256  (also hosts W4 buffers early)
    float* Y2     = (float*)(ws + 20217856);       // 4096*512
    float* Y3     = (float*)(ws + 28606464);       // 4096*1024
    float* feat   = (float*)(ws + 45383680);       // 32*1024
    float* fb1    = (float*)(ws + 45514752);       // 32*512
    float* fb2    = (float*)(ws + 45580288);       // 32*256

    // W4 buffers live in the Y1 region: consumed by mlp1/mlp2 BEFORE gemm1 writes Y1.
    float4* W4s10 = (float4*)(ws + 16023552);      // 1*64
    float4* W4s11 = (float4*)(ws + 16024576);      // 16*64
    float4* W4s12 = (float4*)(ws + 16040960);      // 16*128
    float4* W4s20 = (float4*)(ws + 16073728);      // 33*128
    float4* W4s21 = (float4*)(ws + 16141312);      // 32*128
    float4* W4s22 = (float4*)(ws + 16206848);      // 32*256

    wt4all_kernel<<<77, 256, 0, stream>>>(s1w0, W4s10, s1w1, W4s11, s1w2, W4s12,
                                          s2w0, W4s20, s2w1, W4s21, s2w2, W4s22);

    // Stage 1
    fps_kernel<4096, 512, 256, true><<<32, 256, 0, stream>>>(xyz, l1_xyz);
    bq_kernel<4096, 32, true, 1024><<<1024, 1024, 0, stream>>>(
        (float)(0.2 * 0.2), xyz, l1_xyz, gidx1, 512);
    {
        dim3 g(256, 32);
        mlp1_kernel<<<g, 256, 0, stream>>>(xyz, l1_xyz, gidx1,
            W4s10, s1b0, W4s11, s1b1, W4s12, s1b2, l1p);
    }

    // Stage 2
    fps_kernel<512, 128, 64, false><<<32, 64, 0, stream>>>(l1_xyz, l2_xyz);
    bq_kernel<512, 64, false, 1024><<<256, 1024, 0, stream>>>(
        (float)(0.4 * 0.4), l1_xyz, l2_xyz, gidx2, 128);
    mlp2_kernel<<<4096, 256, 0, stream>>>(l1_xyz, l1p, l2_xyz, gidx2,
        W4s20, s2b0, W4s21, s2b1, W4s22, s2b2, X3);

    // Stage 3 (group-all MLP as GEMMs over 4096 rows)
    {
        dim3 g1(64, 4);  gemm_kernel<true><<<g1, 256, 0, stream>>>(X3, s3w0, s3b0, Y1, 4096, 259, 256);
        dim3 g2(64, 8);  gemm_kernel<true><<<g2, 256, 0, stream>>>(Y1, s3w1, s3b1, Y2, 4096, 256, 512);
        dim3 g3(64, 16); gemm_kernel<true><<<g3, 256, 0, stream>>>(Y2, s3w2, s3b2, Y3, 4096, 512, 1024);
    }
    max128_kernel<<<128, 256, 0, stream>>>(Y3, feat);

    // FC head
    {
        dim3 g1(1, 8); gemm_kernel<true><<<g1, 256, 0, stream>>>(feat, f1w, f1b, fb1, 32, 1024, 512);
        dim3 g2(1, 4); gemm_kernel<true><<<g2, 256, 0, stream>>>(fb1, f2w, f2b, fb2, 32, 512, 256);
        dim3 g3(1, 1); gemm_kernel<false><<<g3, 256, 0, stream>>>(fb2, f3w, f3b, (float*)d_out, 32, 256, 6);
    }
    (void)in_sizes; (void)n_in; (void)out_size; (void)ws_size;
}

// Round 5
// 1649.597 us; speedup vs baseline: 1.0681x; 1.0681x over previous
//
#include <hip/hip_runtime.h>
#include <hip/hip_bf16.h>

// ---------------------------------------------------------------------------
// PointNet++ critic forward. fp32. B=32, N=4096.
// R5: dense layers back to runtime-KC explicit prefetch (R3 schedule, proven
// 83% VALUBusy), now as x2 ping-pong (wa/wb) -> no wc=wn register copies.
// bq (LDS-shared) and fps (register coords) kept from R4.
// ---------------------------------------------------------------------------

// ======================= DPP wave64 max-reduce (u64) =======================
template<int CTRL>
__device__ __forceinline__ unsigned long long dpp_mov_u64(unsigned long long x) {
    const int lo = (int)(unsigned)(x & 0xffffffffull);
    const int hi = (int)(unsigned)(x >> 32);
    const int nlo = __builtin_amdgcn_update_dpp(lo, lo, CTRL, 0xf, 0xf, false);
    const int nhi = __builtin_amdgcn_update_dpp(hi, hi, CTRL, 0xf, 0xf, false);
    return ((unsigned long long)(unsigned)nhi << 32) | (unsigned)nlo;
}

__device__ __forceinline__ unsigned long long wave_max_u64(unsigned long long x) {
    unsigned long long y;
    y = dpp_mov_u64<0x111>(x); if (y > x) x = y;   // row_shr:1
    y = dpp_mov_u64<0x112>(x); if (y > x) x = y;   // row_shr:2
    y = dpp_mov_u64<0x114>(x); if (y > x) x = y;   // row_shr:4
    y = dpp_mov_u64<0x118>(x); if (y > x) x = y;   // row_shr:8
    y = dpp_mov_u64<0x142>(x); if (y > x) x = y;   // row_bcast:15
    y = dpp_mov_u64<0x143>(x); if (y > x) x = y;   // row_bcast:31
    return x;
}

// ============================ FPS ==========================================
template<int N, int S, int NT, bool CHW>
__global__ __launch_bounds__(NT)
void fps_kernel(const float* __restrict__ xyz, float* __restrict__ new_xyz) {
    constexpr int P  = N / NT;
    constexpr int NW = NT / 64;
    __shared__ __align__(16) float4 sxyz[N];
    __shared__ __align__(16) unsigned long long rv[2][NW > 1 ? NW : 2];
    const int b = blockIdx.x, t = threadIdx.x;
    float px[P], py[P], pz[P], dist[P];
    if (CHW) {
        const float* base = xyz + (size_t)b * 3 * N;
        #pragma unroll
        for (int p = 0; p < P; ++p) {
            const int i = p * NT + t;
            px[p] = base[i]; py[p] = base[N + i]; pz[p] = base[2 * N + i];
            sxyz[i] = make_float4(px[p], py[p], pz[p], 0.0f);
        }
    } else {
        const float* base = xyz + (size_t)b * N * 3;
        #pragma unroll
        for (int p = 0; p < P; ++p) {
            const int i = p * NT + t;
            px[p] = base[i*3]; py[p] = base[i*3+1]; pz[p] = base[i*3+2];
            sxyz[i] = make_float4(px[p], py[p], pz[p], 0.0f);
        }
    }
    #pragma unroll
    for (int p = 0; p < P; ++p) dist[p] = 1e10f;
    __syncthreads();
    int far = 0;
    float* out = new_xyz + (size_t)b * S * 3;
    for (int j = 0; j < S; ++j) {
        const float4 cen = sxyz[far];            // broadcast b128
        if (t == 0) { out[j*3+0] = cen.x; out[j*3+1] = cen.y; out[j*3+2] = cen.z; }
        float bv = -1.0f; int bi = 0;
        #pragma unroll
        for (int p = 0; p < P; ++p) {
            const int i = p * NT + t;
            const float dx = px[p] - cen.x, dy = py[p] - cen.y, dz = pz[p] - cen.z;
            // match reference rounding exactly: no FMA contraction
            const float d = __fadd_rn(__fadd_rn(__fmul_rn(dx, dx), __fmul_rn(dy, dy)), __fmul_rn(dz, dz));
            const float nd = fminf(dist[p], d);
            dist[p] = nd;
            if (nd > bv) { bv = nd; bi = i; }    // strict > keeps smallest i
        }
        unsigned long long pk =
            ((unsigned long long)__float_as_uint(bv) << 32) | (unsigned)(N - 1 - bi);
        pk = wave_max_u64(pk);
        if constexpr (NW > 1) {
            const int sl = j & 1;
            if ((t & 63) == 63) rv[sl][t >> 6] = pk;
            __syncthreads();
            unsigned long long best = rv[sl][0];
            #pragma unroll
            for (int w = 1; w < NW; ++w) { const unsigned long long v = rv[sl][w]; if (v > best) best = v; }
            far = N - 1 - (int)(best & 0xffffffffull);
        } else {
            far = N - 1 - __builtin_amdgcn_readlane((int)(pk & 0xffffffffull), 63);
        }
    }
}

// ============================ Ball query ===================================
template<int N, int NS, bool CHW, int NT>
__global__ __launch_bounds__(NT)
void bq_kernel(float r2, const float* __restrict__ xyz, const float* __restrict__ cen,
               int* __restrict__ gidx, int S) {
    constexpr int WPB = NT / 64;
    __shared__ __align__(16) float4 sp[N];
    const int t = threadIdx.x, lane = t & 63, w = t >> 6;
    const int cen0 = blockIdx.x * WPB;
    const int b = cen0 / S;                     // WPB divides S -> same batch
    if (CHW) {
        const float* base = xyz + (size_t)b * 3 * N;
        for (int i = t; i < N; i += NT)
            sp[i] = make_float4(base[i], base[N + i], base[2 * N + i], 0.0f);
    } else {
        const float* base = xyz + (size_t)b * N * 3;
        for (int i = t; i < N; i += NT)
            sp[i] = make_float4(base[i*3], base[i*3+1], base[i*3+2], 0.0f);
    }
    __syncthreads();
    const int wid = cen0 + w;
    const float cx = cen[(size_t)wid*3+0], cy = cen[(size_t)wid*3+1], cz = cen[(size_t)wid*3+2];
    int* out = gidx + (size_t)wid * NS;
    int cnt = 0, first = -1;
    for (int b0 = 0; b0 < N; b0 += 64) {
        const float4 p = sp[b0 + lane];
        const float dx = p.x - cx, dy = p.y - cy, dz = p.z - cz;
        const float d = __fadd_rn(__fadd_rn(__fmul_rn(dx, dx), __fmul_rn(dy, dy)), __fmul_rn(dz, dz));
        const bool in = (d <= r2);
        const unsigned long long m = __ballot(in);
        if (first < 0 && m != 0ull) first = b0 + __ffsll((unsigned long long)m) - 1;
        const int pos = cnt + (int)__popcll(m & ((1ull << lane) - 1ull));
        if (in && pos < NS) out[pos] = b0 + lane;
        cnt += (int)__popcll(m);
        if (cnt >= NS) break;
    }
    if (cnt < NS)
        for (int k = cnt + lane; k < NS; k += 64) out[k] = first;
}

// ==================== weight pre-transpose (fused, one launch) =============
__device__ __forceinline__ void wt4_one(const float* __restrict__ w, float4* __restrict__ out,
                                        int O, int K, int reorder, int i) {
    const int o = i % O, cc = i / O;
    float v[4];
    #pragma unroll
    for (int u = 0; u < 4; ++u) {
        const int cp = cc * 4 + u;
        int c;
        if (reorder) c = (cp < K - 3) ? cp + 3 : (cp < K ? cp - (K - 3) : -1);
        else         c = (cp < K) ? cp : -1;
        v[u] = (c >= 0) ? w[(size_t)o * K + c] : 0.0f;
    }
    out[(size_t)cc * O + o] = make_float4(v[0], v[1], v[2], v[3]);
}

__global__ __launch_bounds__(256)
void wt4all_kernel(const float* w10, float4* o10, const float* w11, float4* o11,
                   const float* w12, float4* o12, const float* w20, float4* o20,
                   const float* w21, float4* o21, const float* w22, float4* o22) {
    int i = blockIdx.x * 256 + threadIdx.x;
    if (i < 64)        { wt4_one(w10, o10,  64,   3, 0, i); return; }       i -= 64;
    if (i < 1024)      { wt4_one(w11, o11,  64,  64, 0, i); return; }       i -= 1024;
    if (i < 2048)      { wt4_one(w12, o12, 128,  64, 0, i); return; }       i -= 2048;
    if (i < 4224)      { wt4_one(w20, o20, 128, 131, 1, i); return; }       i -= 4224;
    if (i < 4096)      { wt4_one(w21, o21, 128, 128, 0, i); return; }       i -= 4096;
    if (i < 8192)      { wt4_one(w22, o22, 256, 128, 0, i); return; }
}

// ===================== dense layer (global weights, LDS acts) ==============
// Runtime KC (keeps the R3 schedule the compiler handled well) + x2 ping-pong
// explicit prefetch: wa/wb alternate, no register copies.
template<int O, int SIN, int SOUT>
__device__ __forceinline__ void dense_relu(
    const float4* __restrict__ W4, const float* __restrict__ bias,
    const float* __restrict__ in, float* __restrict__ out, int KC, int t) {
    constexpr int Q   = O / 4;
    constexpr int RPT = Q / 4;
    constexpr int NB  = (RPT + 7) / 8;
    constexpr int RB  = RPT < 8 ? RPT : 8;
    const int q = t & (Q - 1);
    const int rg = t / Q;
    const int n0 = rg * RPT;
    float bb[4];
    #pragma unroll
    for (int j = 0; j < 4; ++j) bb[j] = bias[q + Q * j];
    #pragma unroll
    for (int nb = 0; nb < NB; ++nb) {
        float acc[RB][4];
        #pragma unroll
        for (int k = 0; k < RB; ++k)
            #pragma unroll
            for (int j = 0; j < 4; ++j) acc[k][j] = bb[j];
        const float* inb = in + (n0 + nb * 8) * SIN;
        float4 wa[4], wb[4];
        #pragma unroll
        for (int j = 0; j < 4; ++j) wa[j] = W4[q + Q * j];
        int cc = 0;
        for (; cc + 2 <= KC; cc += 2) {
            #pragma unroll
            for (int j = 0; j < 4; ++j) wb[j] = W4[(size_t)(cc + 1) * O + q + Q * j];
            #pragma unroll
            for (int k = 0; k < RB; ++k) {
                const float4 xv = *(const float4*)&inb[k * SIN + cc * 4];
                #pragma unroll
                for (int j = 0; j < 4; ++j)
                    acc[k][j] += wa[j].x * xv.x + wa[j].y * xv.y + wa[j].z * xv.z + wa[j].w * xv.w;
            }
            const int cn = (cc + 2 < KC) ? cc + 2 : cc;
            #pragma unroll
            for (int j = 0; j < 4; ++j) wa[j] = W4[(size_t)cn * O + q + Q * j];
            #pragma unroll
            for (int k = 0; k < RB; ++k) {
                const float4 xv = *(const float4*)&inb[k * SIN + cc * 4 + 4];
                #pragma unroll
                for (int j = 0; j < 4; ++j)
                    acc[k][j] += wb[j].x * xv.x + wb[j].y * xv.y + wb[j].z * xv.z + wb[j].w * xv.w;
            }
        }
        if (cc < KC) {   // odd tail (wa holds weights[cc])
            #pragma unroll
            for (int k = 0; k < RB; ++k) {
                const float4 xv = *(const float4*)&inb[k * SIN + cc * 4];
                #pragma unroll
                for (int j = 0; j < 4; ++j)
                    acc[k][j] += wa[j].x * xv.x + wa[j].y * xv.y + wa[j].z * xv.z + wa[j].w * xv.w;
            }
        }
        #pragma unroll
        for (int k = 0; k < RB; ++k)
            #pragma unroll
            for (int j = 0; j < 4; ++j)
                out[(n0 + nb * 8 + k) * SOUT + q + Q * j] = fmaxf(acc[k][j], 0.0f);
    }
}

template<int O, int SIN>
__device__ __forceinline__ void dense_relu_max(
    const float4* __restrict__ W4, const float* __restrict__ bias,
    const float* __restrict__ in, float* __restrict__ red, int KC, int t) {
    constexpr int Q   = O / 4;
    constexpr int RPT = Q / 4;
    constexpr int NB  = (RPT + 7) / 8;
    constexpr int RB  = RPT < 8 ? RPT : 8;
    const int q = t & (Q - 1);
    const int rg = t / Q;
    const int n0 = rg * RPT;
    float bb[4], m[4];
    #pragma unroll
    for (int j = 0; j < 4; ++j) { bb[j] = bias[q + Q * j]; m[j] = 0.0f; }
    #pragma unroll
    for (int nb = 0; nb < NB; ++nb) {
        float acc[RB][4];
        #pragma unroll
        for (int k = 0; k < RB; ++k)
            #pragma unroll
            for (int j = 0; j < 4; ++j) acc[k][j] = bb[j];
        const float* inb = in + (n0 + nb * 8) * SIN;
        float4 wa[4], wb[4];
        #pragma unroll
        for (int j = 0; j < 4; ++j) wa[j] = W4[q + Q * j];
        int cc = 0;
        for (; cc + 2 <= KC; cc += 2) {
            #pragma unroll
            for (int j = 0; j < 4; ++j) wb[j] = W4[(size_t)(cc + 1) * O + q + Q * j];
            #pragma unroll
            for (int k = 0; k < RB; ++k) {
                const float4 xv = *(const float4*)&inb[k * SIN + cc * 4];
                #pragma unroll
                for (int j = 0; j < 4; ++j)
                    acc[k][j] += wa[j].x * xv.x + wa[j].y * xv.y + wa[j].z * xv.z + wa[j].w * xv.w;
            }
            const int cn = (cc + 2 < KC) ? cc + 2 : cc;
            #pragma unroll
            for (int j = 0; j < 4; ++j) wa[j] = W4[(size_t)cn * O + q + Q * j];
            #pragma unroll
            for (int k = 0; k < RB; ++k) {
                const float4 xv = *(const float4*)&inb[k * SIN + cc * 4 + 4];
                #pragma unroll
                for (int j = 0; j < 4; ++j)
                    acc[k][j] += wb[j].x * xv.x + wb[j].y * xv.y + wb[j].z * xv.z + wb[j].w * xv.w;
            }
        }
        if (cc < KC) {
            #pragma unroll
            for (int k = 0; k < RB; ++k) {
                const float4 xv = *(const float4*)&inb[k * SIN + cc * 4];
                #pragma unroll
                for (int j = 0; j < 4; ++j)
                    acc[k][j] += wa[j].x * xv.x + wa[j].y * xv.y + wa[j].z * xv.z + wa[j].w * xv.w;
            }
        }
        #pragma unroll
        for (int k = 0; k < RB; ++k)
            #pragma unroll
            for (int j = 0; j < 4; ++j) m[j] = fmaxf(m[j], fmaxf(acc[k][j], 0.0f));
    }
    #pragma unroll
    for (int j = 0; j < 4; ++j) red[rg * O + q + Q * j] = m[j];
}

// ============================ MLP stage 1 ==================================
__global__ __launch_bounds__(256)
void mlp1_kernel(const float* __restrict__ xyz, const float* __restrict__ l1xyz,
                 const int* __restrict__ gidx,
                 const float4* __restrict__ W40, const float* __restrict__ b0,
                 const float4* __restrict__ W41, const float* __restrict__ b1,
                 const float4* __restrict__ W42, const float* __restrict__ b2,
                 float* __restrict__ l1p) {
    __shared__ __align__(16) float g[64 * 4];
    __shared__ __align__(16) float h1[64 * 68];
    __shared__ __align__(16) float h2[64 * 68];
    __shared__ float red[1024];
    const int t = threadIdx.x;
    const int b = blockIdx.y, s0 = blockIdx.x * 2;
    {
        const int n = t >> 2, c = t & 3;
        const int s = s0 + (n >> 5);
        const int gi = gidx[((size_t)b * 512 + s) * 32 + (n & 31)];
        float v = 0.0f;
        if (c < 3) v = xyz[(size_t)b * 3 * 4096 + c * 4096 + gi] - l1xyz[((size_t)b * 512 + s) * 3 + c];
        g[n * 4 + c] = v;
    }
    __syncthreads();
    dense_relu<64, 4, 68>(W40, b0, g, h1, 1, t);
    __syncthreads();
    dense_relu<64, 68, 68>(W41, b1, h1, h2, 16, t);
    __syncthreads();
    dense_relu_max<128, 68>(W42, b2, h2, red, 16, t);
    __syncthreads();
    {
        const int half = t >> 7, o = t & 127;
        float v = red[(half * 4 + 0) * 128 + o];
        v = fmaxf(v, red[(half * 4 + 1) * 128 + o]);
        v = fmaxf(v, red[(half * 4 + 2) * 128 + o]);
        v = fmaxf(v, red[(half * 4 + 3) * 128 + o]);
        l1p[((size_t)b * 512 + s0 + half) * 128 + o] = v;
    }
}

// ============================ MLP stage 2 ==================================
__global__ __launch_bounds__(256)
void mlp2_kernel(const float* __restrict__ l1xyz, const float* __restrict__ l1p,
                 const float* __restrict__ l2xyz, const int* __restrict__ gidx,
                 const float4* __restrict__ W40, const float* __restrict__ b0,
                 const float4* __restrict__ W41, const float* __restrict__ b1,
                 const float4* __restrict__ W42, const float* __restrict__ b2,
                 float* __restrict__ X3) {
    __shared__ __align__(16) float xb[64 * 132];
    __shared__ __align__(16) float h1[64 * 128];
    __shared__ float red[1024];
    __shared__ int sg[64];
    const int t = threadIdx.x, bs = blockIdx.x, b = bs >> 7;
    if (t < 64) sg[t] = gidx[(size_t)bs * 64 + t];
    if (t < 3)  X3[(size_t)bs * 259 + t] = l2xyz[(size_t)bs * 3 + t];   // raw coords
    __syncthreads();
    {
        for (int i = t; i < 64 * 32; i += 256) {
            const int n = i >> 5, cc = i & 31;
            const float4 v = *(const float4*)&l1p[((size_t)b * 512 + sg[n]) * 128 + cc * 4];
            *(float4*)&xb[n * 132 + cc * 4] = v;
        }
        if (t < 192) {
            const int n = t / 3, c = t % 3;
            xb[n * 132 + 128 + c] =
                l1xyz[((size_t)b * 512 + sg[n]) * 3 + c] - l2xyz[(size_t)bs * 3 + c];
        }
        if (t < 64) xb[t * 132 + 131] = 0.0f;
    }
    __syncthreads();
    dense_relu<128, 132, 128>(W40, b0, xb, h1, 33, t);
    __syncthreads();
    dense_relu<128, 128, 128>(W41, b1, h1, xb, 32, t);
    __syncthreads();
    dense_relu_max<256, 128>(W42, b2, xb, red, 32, t);
    __syncthreads();
    {
        float v = red[t];
        v = fmaxf(v, red[256 + t]);
        v = fmaxf(v, red[512 + t]);
        v = fmaxf(v, red[768 + t]);
        X3[(size_t)bs * 259 + 3 + t] = v;
    }
}

// ============================ Generic GEMM =================================
template<bool RELU>
__global__ __launch_bounds__(256)
void gemm_kernel(const float* __restrict__ A, const float* __restrict__ W,
                 const float* __restrict__ bias, float* __restrict__ C,
                 int M, int K, int O) {
    __shared__ __align__(16) float At[32*68];
    __shared__ __align__(16) float Wt[32*68];
    const int t = threadIdx.x;
    const int mtile = blockIdx.x * 64, otile = blockIdx.y * 64;
    const int tx = t & 15, ty = t >> 4;
    float acc[4][4];
    #pragma unroll
    for (int i = 0; i < 4; ++i)
        #pragma unroll
        for (int j = 0; j < 4; ++j) acc[i][j] = 0.0f;
    const int kk = t & 31, r0 = t >> 5;
    for (int k0 = 0; k0 < K; k0 += 32) {
        #pragma unroll
        for (int rr = 0; rr < 8; ++rr) {
            const int row = r0 + rr * 8;
            const int m = mtile + row, o = otile + row, k = k0 + kk;
            At[kk*68 + row] = (m < M && k < K) ? A[(size_t)m*K + k] : 0.0f;
            Wt[kk*68 + row] = (o < O && k < K) ? W[(size_t)o*K + k] : 0.0f;
        }
        __syncthreads();
        #pragma unroll
        for (int k2 = 0; k2 < 32; ++k2) {
            const float4 av = *(const float4*)&At[k2*68 + tx*4];
            const float4 wv = *(const float4*)&Wt[k2*68 + ty*4];
            const float a[4] = {av.x, av.y, av.z, av.w};
            const float w[4] = {wv.x, wv.y, wv.z, wv.w};
            #pragma unroll
            for (int i = 0; i < 4; ++i)
                #pragma unroll
                for (int j = 0; j < 4; ++j) acc[i][j] += a[i] * w[j];
        }
        __syncthreads();
    }
    #pragma unroll
    for (int i = 0; i < 4; ++i) {
        const int m = mtile + tx*4 + i;
        if (m >= M) continue;
        #pragma unroll
        for (int j = 0; j < 4; ++j) {
            const int o = otile + ty*4 + j;
            if (o >= O) continue;
            float v = acc[i][j] + bias[o];
            if (RELU) v = fmaxf(v, 0.0f);
            C[(size_t)m*O + o] = v;
        }
    }
}

// ============================ small utilities ==============================
__global__ __launch_bounds__(256)
void max128_kernel(const float* __restrict__ Y, float* __restrict__ feat) {
    const int idx = blockIdx.x * 256 + threadIdx.x;  // 32*1024
    const int b = idx >> 10, o = idx & 1023;
    const float* p = Y + (size_t)b * 128 * 1024 + o;
    float m = p[0];
    for (int n = 1; n < 128; ++n) m = fmaxf(m, p[(size_t)n * 1024]);
    feat[idx] = m;
}

// ============================ launch =======================================
extern "C" void kernel_launch(void* const* d_in, const int* in_sizes, int n_in,
                              void* d_out, int out_size, void* d_ws, size_t ws_size,
                              hipStream_t stream) {
    const float* xyz  = (const float*)d_in[0];
    const float* s1w0 = (const float*)d_in[1];  const float* s1b0 = (const float*)d_in[2];
    const float* s1w1 = (const float*)d_in[3];  const float* s1b1 = (const float*)d_in[4];
    const float* s1w2 = (const float*)d_in[5];  const float* s1b2 = (const float*)d_in[6];
    const float* s2w0 = (const float*)d_in[7];  const float* s2b0 = (const float*)d_in[8];
    const float* s2w1 = (const float*)d_in[9];  const float* s2b1 = (const float*)d_in[10];
    const float* s2w2 = (const float*)d_in[11]; const float* s2b2 = (const float*)d_in[12];
    const float* s3w0 = (const float*)d_in[13]; const float* s3b0 = (const float*)d_in[14];
    const float* s3w1 = (const float*)d_in[15]; const float* s3b1 = (const float*)d_in[16];
    const float* s3w2 = (const float*)d_in[17]; const float* s3b2 = (const float*)d_in[18];
    const float* f1w  = (const float*)d_in[19]; const float* f1b  = (const float*)d_in[20];
    const float* f2w  = (const float*)d_in[21]; const float* f2b  = (const float*)d_in[22];
    const float* f3w  = (const float*)d_in[23]; const float* f3b  = (const float*)d_in[24];

    char* ws = (char*)d_ws;
    float* l1_xyz = (float*)(ws + 0);              // 32*512*3
    int*   gidx1  = (int*)  (ws + 196608);         // 32*512*32
    float* l1p    = (float*)(ws + 2293760);        // 32*512*128
    float* l2_xyz = (float*)(ws + 10682368);       // 32*128*3
    int*   gidx2  = (int*)  (ws + 10731520);       // 32*128*64
    float* X3     = (float*)(ws + 11780096);       // 32*128*259
    float* Y1     = (float*)(ws + 16023552);       // 4096*256  (also hosts W4 buffers early)
    float* Y2     = (float*)(ws + 20217856);       // 4096*512
    float* Y3     = (float*)(ws + 28606464);       // 4096*1024
    float* feat   = (float*)(ws + 45383680);       // 32*1024
    float* fb1    = (float*)(ws + 45514752);       // 32*512
    float* fb2    = (float*)(ws + 45580288);       // 32*256

    // W4 buffers live in the Y1 region: consumed by mlp1/mlp2 BEFORE gemm1 writes Y1.
    float4* W4s10 = (float4*)(ws + 16023552);      // 1*64
    float4* W4s11 = (float4*)(ws + 16024576);      // 16*64
    float4* W4s12 = (float4*)(ws + 16040960);      // 16*128
    float4* W4s20 = (float4*)(ws + 16073728);      // 33*128
    float4* W4s21 = (float4*)(ws + 16141312);      // 32*128
    float4* W4s22 = (float4*)(ws + 16206848);      // 32*256

    wt4all_kernel<<<77, 256, 0, stream>>>(s1w0, W4s10, s1w1, W4s11, s1w2, W4s12,
                                          s2w0, W4s20, s2w1, W4s21, s2w2, W4s22);

    // Stage 1
    fps_kernel<4096, 512, 256, true><<<32, 256, 0, stream>>>(xyz, l1_xyz);
    bq_kernel<4096, 32, true, 1024><<<1024, 1024, 0, stream>>>(
        (float)(0.2 * 0.2), xyz, l1_xyz, gidx1, 512);
    {
        dim3 g(256, 32);
        mlp1_kernel<<<g, 256, 0, stream>>>(xyz, l1_xyz, gidx1,
            W4s10, s1b0, W4s11, s1b1, W4s12, s1b2, l1p);
    }

    // Stage 2
    fps_kernel<512, 128, 64, false><<<32, 64, 0, stream>>>(l1_xyz, l2_xyz);
    bq_kernel<512, 64, false, 1024><<<256, 1024, 0, stream>>>(
        (float)(0.4 * 0.4), l1_xyz, l2_xyz, gidx2, 128);
    mlp2_kernel<<<4096, 256, 0, stream>>>(l1_xyz, l1p, l2_xyz, gidx2,
        W4s20, s2b0, W4s21, s2b1, W4s22, s2b2, X3);

    // Stage 3 (group-all MLP as GEMMs over 4096 rows)
    {
        dim3 g1(64, 4);  gemm_kernel<true><<<g1, 256, 0, stream>>>(X3, s3w0, s3b0, Y1, 4096, 259, 256);
        dim3 g2(64, 8);  gemm_kernel<true><<<g2, 256, 0, stream>>>(Y1, s3w1, s3b1, Y2, 4096, 256, 512);
        dim3 g3(64, 16); gemm_kernel<true><<<g3, 256, 0, stream>>>(Y2, s3w2, s3b2, Y3, 4096, 512, 1024);
    }
    max128_kernel<<<128, 256, 0, stream>>>(Y3, feat);

    // FC head
    {
        dim3 g1(1, 8); gemm_kernel<true><<<g1, 256, 0, stream>>>(feat, f1w, f1b, fb1, 32, 1024, 512);
        dim3 g2(1, 4); gemm_kernel<true><<<g2, 256, 0, stream>>>(fb1, f2w, f2b, fb2, 32, 512, 256);
        dim3 g3(1, 1); gemm_kernel<false><<<g3, 256, 0, stream>>>(fb2, f3w, f3b, (float*)d_out, 32, 256, 6);
    }
    (void)in_sizes; (void)n_in; (void)out_size; (void)ws_size;
}